// Round 16
// baseline (388.804 us; speedup 1.0000x reference)
//
#include <hip/hip_runtime.h>

#define NN 100000
#define NE 1000000
#define NCLS 32
#define NB 391            // ceil(NN/256)
#define GN 32             // nodes per k_agg group
#define NGROUPS (NN/GN)   // 3125
#define UVG ((NN+63)/64)  // 1563 uv groups of 64 nodes

typedef __bf16 bf16x8 __attribute__((ext_vector_type(8)));
typedef float f32x16 __attribute__((ext_vector_type(16)));

__device__ __forceinline__ int imin(int a, int b){ return a < b ? a : b; }

// pack hi16 of two f32 into one u32: {hi16(f1) : hi16(f0)}  (f0 -> low half)
__device__ __forceinline__ unsigned pk_hi(unsigned u1, unsigned u0){
  return __builtin_amdgcn_perm(u1, u0, 0x07060302u);
}
__device__ __forceinline__ unsigned pk_lo(float f0, float f1, unsigned u0, unsigned u1){
  float r0 = f0 - __uint_as_float(u0 & 0xFFFF0000u);
  float r1 = f1 - __uint_as_float(u1 & 0xFFFF0000u);
  return pk_hi(__float_as_uint(r1), __float_as_uint(r0));
}
__device__ __forceinline__ f32x16 mfma_b(uint4 a, uint4 b, f32x16 c){
  bf16x8 av, bv;
  __builtin_memcpy(&av, &a, 16);
  __builtin_memcpy(&bv, &b, 16);
  return __builtin_amdgcn_mfma_f32_32x32x16_bf16(av, bv, c, 0, 0, 0);
}
__device__ __forceinline__ int crow(int r, int half){ return (r&3) + 8*(r>>2) + 4*half; }

// ---------- one-shot setup: all weight fragments + bc + zero deg ----------
__global__ void k_setup(const float* __restrict__ W1_lin, const float* __restrict__ b1_lin,
                        const float* __restrict__ W1_post, const float* __restrict__ b1_post,
                        const float* __restrict__ W2_lin, const float* __restrict__ b2_lin,
                        const float* __restrict__ W2_post, const float* __restrict__ b2_post,
                        const float* __restrict__ W1_pre, const float* __restrict__ W2_pre,
                        const float* __restrict__ Wf,
                        uint4* __restrict__ Wcf, uint4* __restrict__ Wpf,
                        uint4* __restrict__ Wff, float* __restrict__ bc,
                        int* __restrict__ deg){
  const int blk = blockIdx.x, tid = threadIdx.x;
  if (blk < 16){
    int i = blk*256 + tid;                    // [0, 4096)
    int layer = i >> 11;
    int t = (i >> 10) & 1, step = (i >> 6) & 15, lane = i & 63;
    const float* Wlin  = layer ? W2_lin  : W1_lin;
    const float* Wpost = layer ? W2_post : W1_post;
    int col = t*32 + (lane & 31);
    int k0 = step*16 + ((lane >> 5) << 3);
    unsigned hi[4], lo[4];
    for (int p = 0; p < 4; p++){
      float f0 = 0.f, f1 = 0.f;
      for (int j = 0; j < 64; j++){
        float wl = Wlin[col*64 + j];
        f0 += wl * Wpost[j*256 + k0 + 2*p];
        f1 += wl * Wpost[j*256 + k0 + 2*p + 1];
      }
      unsigned u0 = __float_as_uint(f0), u1 = __float_as_uint(f1);
      hi[p] = pk_hi(u1, u0);
      lo[p] = pk_lo(f0, f1, u0, u1);
    }
    uint4* base = Wcf + layer*4096;
    base[t*1024     + step*64 + lane] = make_uint4(hi[0],hi[1],hi[2],hi[3]);
    base[(2+t)*1024 + step*64 + lane] = make_uint4(lo[0],lo[1],lo[2],lo[3]);
  } else if (blk < 24){
    int i = (blk-16)*256 + tid;               // [0, 2048)
    int layer = i >> 10;
    int t = (i >> 8) & 3, st = (i >> 6) & 3, lane = i & 63;
    const float* Wpre = layer ? W2_pre : W1_pre;
    int col = t*32 + (lane & 31);             // 0..127 (u | v)
    int o = col & 63, koff = (col >> 6) * 64;
    int k0 = st*16 + ((lane >> 5) << 3);
    unsigned hi[4], lo[4];
    for (int p = 0; p < 4; p++){
      float f0 = Wpre[o*128 + koff + k0 + 2*p];
      float f1 = Wpre[o*128 + koff + k0 + 2*p + 1];
      unsigned u0 = __float_as_uint(f0), u1 = __float_as_uint(f1);
      hi[p] = pk_hi(u1, u0);
      lo[p] = pk_lo(f0, f1, u0, u1);
    }
    uint4* base = Wpf + layer*2048 + t*512;
    base[st*64 + lane]       = make_uint4(hi[0],hi[1],hi[2],hi[3]);
    base[256 + st*64 + lane] = make_uint4(lo[0],lo[1],lo[2],lo[3]);
  } else if (blk == 24){
    int st = tid >> 6, lane = tid & 63;       // 256 threads exactly
    int cls = lane & 31;
    int k0 = st*16 + ((lane >> 5) << 3);
    unsigned hi[4], lo[4];
    for (int p = 0; p < 4; p++){
      float f0 = Wf[cls*64 + k0 + 2*p];
      float f1 = Wf[cls*64 + k0 + 2*p + 1];
      unsigned u0 = __float_as_uint(f0), u1 = __float_as_uint(f1);
      hi[p] = pk_hi(u1, u0);
      lo[p] = pk_lo(f0, f1, u0, u1);
    }
    Wff[st*64 + lane]       = make_uint4(hi[0],hi[1],hi[2],hi[3]);
    Wff[256 + st*64 + lane] = make_uint4(lo[0],lo[1],lo[2],lo[3]);
  } else if (blk == 25){
    if (tid < 128){
      int layer = tid >> 6, o = tid & 63;
      const float* Wlin  = layer ? W2_lin  : W1_lin;
      const float* blin  = layer ? b2_lin  : b1_lin;
      const float* bpost = layer ? b2_post : b1_post;
      float s = blin[o];
      for (int j = 0; j < 64; j++) s += Wlin[o*64+j] * bpost[j];
      bc[tid] = s;
    }
  } else {
    int i = (blk-26)*256 + tid;
    if (i < NN) deg[i] = 0;
  }
}

// ---------- CSR build ----------
__global__ void k_deg(const int* __restrict__ dst, int* __restrict__ deg){
  int e = blockIdx.x*256 + threadIdx.x;
  if (e < NE) atomicAdd(&deg[dst[e]], 1);
}

__global__ void k_scan1(const int* __restrict__ deg, int* __restrict__ inc,
                        int* __restrict__ part){
  __shared__ int s[256];
  int tid = threadIdx.x;
  int i = blockIdx.x*256 + tid;
  s[tid] = (i < NN) ? deg[i] : 0;
  __syncthreads();
  for (int off = 1; off < 256; off <<= 1){
    int t = (tid >= off) ? s[tid-off] : 0;
    __syncthreads();
    s[tid] += t;
    __syncthreads();
  }
  inc[i] = s[tid];
  if (tid == 255) part[blockIdx.x] = s[255];
}

// each block re-scans all partials in LDS, then emits rowptr + cursor
__global__ void k_scan23(const int* __restrict__ inc, const int* __restrict__ part,
                         const int* __restrict__ deg,
                         int* __restrict__ rowptr, int* __restrict__ cursor){
  __shared__ int s[512];
  int tid = threadIdx.x;
  s[tid] = (tid < NB) ? part[tid] : 0;
  __syncthreads();
  for (int off = 1; off < 512; off <<= 1){
    int t = (tid >= off) ? s[tid-off] : 0;
    __syncthreads();
    s[tid] += t;
    __syncthreads();
  }
  int b = blockIdx.x;
  int base = b ? s[b-1] : 0;
  if (tid < 256){
    int i = b*256 + tid;
    if (i < NN){
      int inclusive = inc[i] + base;
      rowptr[i+1] = inclusive;
      cursor[i] = inclusive - deg[i];
    }
  }
  if (b == 0 && tid == 0) rowptr[0] = 0;
}

__global__ void k_scatter(const int* __restrict__ src, const int* __restrict__ dst,
                          int* __restrict__ cursor, int* __restrict__ srcs){
  int e = blockIdx.x*256 + threadIdx.x;
  if (e < NE){
    int d = dst[e];
    int p = atomicAdd(&cursor[d], 1);
    srcs[p] = src[e];
  }
}

// ---------- per-node pre-transform via MFMA: u(f32) = WpreL*x + b ; vq(bf16-pair) = WpreR*x ----------
__global__ __launch_bounds__(512, 4) void k_uv(
    const float* __restrict__ xin, const uint4* __restrict__ Wpf,
    const float* __restrict__ bpre, float* __restrict__ u, unsigned* __restrict__ vq){
  __shared__ __align__(16) unsigned XH[64*36];
  __shared__ __align__(16) unsigned XL[64*36];
  const int tid = threadIdx.x;
  const int lane = tid & 63;
  const int w = tid >> 6;
  const int t = w >> 1, rg = w & 1;
  const int cc = lane & 31, half = lane >> 5;
  const int col = t*32 + cc;
  uint4 wfr[2][4];
  {
    const uint4* p = Wpf + t*512;
    #pragma unroll
    for (int s = 0; s < 2; s++)
      #pragma unroll
      for (int st = 0; st < 4; st++) wfr[s][st] = p[s*256 + st*64 + lane];
  }
  const float bias = (t < 2) ? bpre[col] : 0.f;
  const int dcol = col & 63;
  const int srow = tid >> 3, sq = tid & 7;

  for (int g = blockIdx.x; g < UVG; g += gridDim.x){
    const int n0 = g*64;
    __syncthreads();                 // previous group's A-frag reads done
    {
      const int node = n0 + srow;
      float4 a = {0,0,0,0}, b = {0,0,0,0};
      if (node < NN){
        a = *(const float4*)&xin[(size_t)node*64 + sq*8];
        b = *(const float4*)&xin[(size_t)node*64 + sq*8 + 4];
      }
      unsigned ax = __float_as_uint(a.x), ay = __float_as_uint(a.y);
      unsigned az = __float_as_uint(a.z), aw = __float_as_uint(a.w);
      unsigned bx = __float_as_uint(b.x), by = __float_as_uint(b.y);
      unsigned bz = __float_as_uint(b.z), bw = __float_as_uint(b.w);
      uint4 hi, lo;
      hi.x = pk_hi(ay, ax); lo.x = pk_lo(a.x, a.y, ax, ay);
      hi.y = pk_hi(aw, az); lo.y = pk_lo(a.z, a.w, az, aw);
      hi.z = pk_hi(by, bx); lo.z = pk_lo(b.x, b.y, bx, by);
      hi.w = pk_hi(bw, bz); lo.w = pk_lo(b.z, b.w, bz, bw);
      *(uint4*)&XH[srow*36 + sq*4] = hi;
      *(uint4*)&XL[srow*36 + sq*4] = lo;
    }
    __syncthreads();
    f32x16 acc = {};
    const int arow = (rg*32 + cc)*36 + half*4;
    #pragma unroll
    for (int st = 0; st < 4; st++){
      uint4 ah = *(const uint4*)&XH[arow + st*8];
      uint4 al = *(const uint4*)&XL[arow + st*8];
      acc = mfma_b(ah, wfr[0][st], acc);
      acc = mfma_b(al, wfr[0][st], acc);
      acc = mfma_b(ah, wfr[1][st], acc);
    }
    if (t < 2){
      #pragma unroll
      for (int r = 0; r < 16; r++){
        int row = n0 + rg*32 + crow(r, half);
        if (row < NN) u[(size_t)row*64 + dcol] = acc[r] + bias;
      }
    } else {
      // pack adjacent columns (even dcol holds pair) -> bf16x2 with RNE
      #pragma unroll
      for (int r = 0; r < 16; r++){
        float val = acc[r];
        float pv = __shfl_xor(val, 1, 64);
        if ((cc & 1) == 0){
          unsigned pk;
          asm("v_cvt_pk_bf16_f32 %0, %1, %2" : "=v"(pk) : "v"(val), "v"(pv));
          int row = n0 + rg*32 + crow(r, half);
          if (row < NN) vq[(size_t)row*32 + (dcol >> 1)] = pk;
        }
      }
    }
  }
}

// ---------- fused CSR gather + MFMA post GEMM (+ fused classifier if EPI==1) ----------
// Round-10 proven gather (dual-node interleave, depth-4, rolling idx prefetch)
// + all-4-node first-batch index preload (hides phase-2's srcs latency).
template<int EPI>
__global__ __launch_bounds__(512, 8) void k_agg(
    const float* __restrict__ xin, const float* __restrict__ u,
    const unsigned* __restrict__ vq,
    const int* __restrict__ rowptr, const int* __restrict__ srcs,
    const uint4* __restrict__ Wcf, const float* __restrict__ bcv,
    const uint4* __restrict__ Wff, const float* __restrict__ bfv,
    float* __restrict__ hout, float* __restrict__ outp){
  __shared__ __align__(16) unsigned Zh[GN*132];
  __shared__ __align__(16) unsigned Zl[GN*132];
  const int tid = threadIdx.x;
  const int lane = tid & 63;
  const int w = tid >> 6;
  const int c = lane & 31;
  const int h = lane >> 5;
  const float bias = (w < 2) ? bcv[w*32 + c] : 0.f;
  const uint4* WH = Wcf + w*1024;
  const uint4* WL = Wcf + (2+w)*1024;

  for (int g = blockIdx.x; g < NGROUPS; g += gridDim.x){
    const int n0 = g*GN;
    __syncthreads();                 // previous group's LDS reads done
    // ---- gather: wave w -> rows w*4 .. w*4+3
    {
      const int nbase = n0 + w*4;
      // row bounds for all 4 nodes (5 loads; contiguous CSR)
      const int r0A = rowptr[nbase];
      const int r1A = rowptr[nbase+1];
      const int r1B = rowptr[nbase+2];
      const int r1C = rowptr[nbase+3];
      const int r1D = rowptr[nbase+4];
      const int r0B = r1A, r0C = r1B, r0D = r1C;
      const int jA = r0A + h, jB = r0B + h, jC = r0C + h, jD = r0D + h;
      const bool hA = (jA + 6 < r1A), hB = (jB + 6 < r1B);
      const bool hC = (jC + 6 < r1C), hD = (jD + 6 < r1D);
      // first-batch indices for ALL FOUR nodes issued upfront
      int a0=0,a1=0,a2=0,a3=0, b0=0,b1=0,b2=0,b3=0;
      int c0=0,c1=0,c2=0,c3=0, d0=0,d1=0,d2=0,d3=0;
      if (hA){ a0=srcs[jA]; a1=srcs[jA+2]; a2=srcs[jA+4]; a3=srcs[jA+6]; }
      if (hB){ b0=srcs[jB]; b1=srcs[jB+2]; b2=srcs[jB+4]; b3=srcs[jB+6]; }
      if (hC){ c0=srcs[jC]; c1=srcs[jC+2]; c2=srcs[jC+4]; c3=srcs[jC+6]; }
      if (hD){ d0=srcs[jD]; d1=srcs[jD+2]; d2=srcs[jD+4]; d3=srcs[jD+6]; }
      #pragma unroll
      for (int pr = 0; pr < 2; pr++){
        #pragma unroll
        for (int sub = 0; sub < 2; sub++){
          const int node = nbase + pr*2 + sub;
          const int r0 = pr ? (sub ? r0D : r0C) : (sub ? r0B : r0A);
          const int r1 = pr ? (sub ? r1D : r1C) : (sub ? r1B : r1A);
          int jj = pr ? (sub ? jD : jC) : (sub ? jB : jA);
          int e0 = pr ? (sub ? d0 : c0) : (sub ? b0 : a0);
          int e1 = pr ? (sub ? d1 : c1) : (sub ? b1 : a1);
          int e2 = pr ? (sub ? d2 : c2) : (sub ? b2 : a2);
          int e3 = pr ? (sub ? d3 : c3) : (sub ? b3 : a3);
          bool have = pr ? (sub ? hD : hC) : (sub ? hB : hA);
          float Sx = 0.f, Sy = 0.f;
          float Mx = -3.402823466e+38f, My = Mx;
          while (have){
            int njj = jj + 8;
            bool more = (njj + 6 < r1);
            int f0=0,f1=0,f2=0,f3=0;
            if (more){ f0=srcs[njj]; f1=srcs[njj+2]; f2=srcs[njj+4]; f3=srcs[njj+6]; }
            unsigned p0 = vq[(size_t)e0*32 + c];
            unsigned p1 = vq[(size_t)e1*32 + c];
            unsigned p2 = vq[(size_t)e2*32 + c];
            unsigned p3 = vq[(size_t)e3*32 + c];
            float x0 = __uint_as_float(p0 << 16), y0 = __uint_as_float(p0 & 0xFFFF0000u);
            float x1 = __uint_as_float(p1 << 16), y1 = __uint_as_float(p1 & 0xFFFF0000u);
            float x2 = __uint_as_float(p2 << 16), y2 = __uint_as_float(p2 & 0xFFFF0000u);
            float x3 = __uint_as_float(p3 << 16), y3 = __uint_as_float(p3 & 0xFFFF0000u);
            Sx += (x0 + x1) + (x2 + x3);
            Sy += (y0 + y1) + (y2 + y3);
            Mx = fmaxf(Mx, fmaxf(fmaxf(x0, x1), fmaxf(x2, x3)));
            My = fmaxf(My, fmaxf(fmaxf(y0, y1), fmaxf(y2, y3)));
            jj = njj; e0=f0; e1=f1; e2=f2; e3=f3; have = more;
          }
          for (; jj < r1; jj += 2){
            unsigned p = vq[(size_t)srcs[jj]*32 + c];
            float x0 = __uint_as_float(p << 16), y0 = __uint_as_float(p & 0xFFFF0000u);
            Sx += x0; Sy += y0;
            Mx = fmaxf(Mx, x0); My = fmaxf(My, y0);
          }
          Sx += __shfl_xor(Sx, 32, 64);
          Sy += __shfl_xor(Sy, 32, 64);
          Mx = fmaxf(Mx, __shfl_xor(Mx, 32, 64));
          My = fmaxf(My, __shfl_xor(My, 32, 64));

          const float2 up = *(const float2*)&u[(size_t)node*64 + 2*c];
          const float2 xv = *(const float2*)&xin[(size_t)node*64 + 2*c];
          const int d = r1 - r0;
          float2 z1, z2, z3;
          if (d > 0){
            float fd = (float)d;
            z1.x = up.x + Sx/fd;  z1.y = up.y + Sy/fd;
            z2.x = up.x + Mx;     z2.y = up.y + My;
            z3.x = fmaf(fd, up.x, Sx); z3.y = fmaf(fd, up.y, Sy);
          } else {
            z1.x=z1.y=z2.x=z2.y=z3.x=z3.y=0.f;   // PyG empty-segment semantics
          }
          const int row = w*4 + pr*2 + sub;
          float2 q[4] = {xv, z1, z2, z3};
          #pragma unroll
          for (int qq = 0; qq < 4; qq++){
            unsigned u0 = __float_as_uint(q[qq].x), u1 = __float_as_uint(q[qq].y);
            if (h == 0) Zh[row*132 + qq*32 + c] = pk_hi(u1, u0);
            else        Zl[row*132 + qq*32 + c] = pk_lo(q[qq].x, q[qq].y, u0, u1);
          }
        }
      }
    }
    __syncthreads();
    // ---- post-GEMM MFMA: waves 0,1
    f32x16 acc = {};
    if (w < 2){
      const int arow = c*132 + h*4;
      #pragma unroll 4
      for (int s = 0; s < 16; s++){
        uint4 ah = *(const uint4*)&Zh[arow + s*8];
        uint4 al = *(const uint4*)&Zl[arow + s*8];
        uint4 bh = WH[s*64 + lane];
        uint4 bl = WL[s*64 + lane];
        acc = mfma_b(ah, bh, acc);
        acc = mfma_b(al, bh, acc);
        acc = mfma_b(ah, bl, acc);
      }
      if (EPI == 0){
        #pragma unroll
        for (int r = 0; r < 16; r++){
          float val = fmaxf(acc[r] + bias, 0.f);
          hout[(size_t)(n0 + crow(r,h))*64 + w*32 + c] = val;
        }
      }
    }
    if (EPI == 1){
      __syncthreads();               // BOTH MFMA waves done READING Zh/Zl
      if (w < 2){
        float* HF = (float*)Zh;      // now safe to reuse Zh
        #pragma unroll
        for (int r = 0; r < 16; r++){
          float val = fmaxf(acc[r] + bias, 0.f);
          HF[crow(r,h)*64 + w*32 + c] = val;
        }
      }
      __syncthreads();               // HF complete
      {
        const float* HF = (const float*)Zh;
        unsigned* HH = Zl;
        unsigned* HL = Zl + 1152;
        const int row = tid >> 4, p4 = tid & 15;
        float4 f = *(const float4*)&HF[row*64 + p4*4];
        unsigned f0 = __float_as_uint(f.x), f1 = __float_as_uint(f.y);
        unsigned f2 = __float_as_uint(f.z), f3 = __float_as_uint(f.w);
        HH[row*36 + p4*2]   = pk_hi(f1, f0);
        HH[row*36 + p4*2+1] = pk_hi(f3, f2);
        HL[row*36 + p4*2]   = pk_lo(f.x, f.y, f0, f1);
        HL[row*36 + p4*2+1] = pk_lo(f.z, f.w, f2, f3);
      }
      __syncthreads();               // HH/HL complete
      if (w == 0){
        f32x16 ac2 = {};
        const unsigned* HH = Zl;
        const unsigned* HL = Zl + 1152;
        const int arow = c*36 + h*4;
        #pragma unroll
        for (int st = 0; st < 4; st++){
          uint4 ah = *(const uint4*)&HH[arow + st*8];
          uint4 al = *(const uint4*)&HL[arow + st*8];
          uint4 bh = Wff[st*64 + lane];
          uint4 bl = Wff[256 + st*64 + lane];
          ac2 = mfma_b(ah, bh, ac2);
          ac2 = mfma_b(al, bh, ac2);
          ac2 = mfma_b(ah, bl, ac2);
        }
        const float bcls = bfv[c];
        #pragma unroll
        for (int r = 0; r < 16; r++)
          outp[(size_t)(n0 + crow(r,h))*NCLS + c] = ac2[r] + bcls;
      }
    }
  }
}

extern "C" void kernel_launch(void* const* d_in, const int* in_sizes, int n_in,
                              void* d_out, int out_size, void* d_ws, size_t ws_size,
                              hipStream_t stream){
  const float* x      = (const float*)d_in[0];
  const int*   ei     = (const int*)  d_in[1];
  const int*   src    = ei;
  const int*   dst    = ei + NE;
  const float* W1_pre = (const float*)d_in[2];
  const float* b1_pre = (const float*)d_in[3];
  const float* W1_post= (const float*)d_in[4];
  const float* b1_post= (const float*)d_in[5];
  const float* W1_lin = (const float*)d_in[6];
  const float* b1_lin = (const float*)d_in[7];
  const float* W2_pre = (const float*)d_in[8];
  const float* b2_pre = (const float*)d_in[9];
  const float* W2_post= (const float*)d_in[10];
  const float* b2_post= (const float*)d_in[11];
  const float* W2_lin = (const float*)d_in[12];
  const float* b2_lin = (const float*)d_in[13];
  const float* Wf     = (const float*)d_in[14];
  const float* bf     = (const float*)d_in[15];
  float* out = (float*)d_out;

  size_t off = 0;
  char* ws = (char*)d_ws;
  auto alloc = [&](size_t bytes){ void* p = ws + off; off += (bytes + 255) & ~(size_t)255; return p; };
  int*      deg    = (int*)     alloc(NN*4);
  int*      rowptr = (int*)     alloc((NN+1)*4);
  int*      cursor = (int*)     alloc(NN*4);
  int*      inc    = (int*)     alloc(NB*256*4);
  int*      part   = (int*)     alloc(512*4);
  int*      srcs   = (int*)     alloc((size_t)NE*4);
  float*    u      = (float*)   alloc((size_t)NN*64*4);
  unsigned* vq     = (unsigned*)alloc((size_t)NN*32*4);
  float*    h1     = (float*)   alloc((size_t)NN*64*4);
  uint4*    Wcf    = (uint4*)   alloc(2*4096*16);
  uint4*    Wpf    = (uint4*)   alloc(4096*16);
  uint4*    Wff    = (uint4*)   alloc(512*16);
  float*    bc     = (float*)   alloc(128*4);

  // 1. all weight fragments + bc + zero deg, in one kernel
  k_setup<<<417, 256, 0, stream>>>(W1_lin, b1_lin, W1_post, b1_post,
                                   W2_lin, b2_lin, W2_post, b2_post,
                                   W1_pre, W2_pre, Wf, Wcf, Wpf, Wff, bc, deg);
  // 2-5. CSR build
  k_deg    <<<(NE+255)/256, 256, 0, stream>>>(dst, deg);
  k_scan1  <<<NB, 256, 0, stream>>>(deg, inc, part);
  k_scan23 <<<NB, 512, 0, stream>>>(inc, part, deg, rowptr, cursor);
  k_scatter<<<(NE+255)/256, 256, 0, stream>>>(src, dst, cursor, srcs);

  // layer 1
  k_uv    <<<UVG, 512, 0, stream>>>(x, Wpf, b1_pre, u, vq);
  k_agg<0><<<NGROUPS, 512, 0, stream>>>(x, u, vq, rowptr, srcs, Wcf, bc,
                                        nullptr, nullptr, h1, nullptr);

  // layer 2 (+ fused classifier; h2 never hits HBM)
  k_uv    <<<UVG, 512, 0, stream>>>(h1, Wpf + 2048, b2_pre, u, vq);
  k_agg<1><<<NGROUPS, 512, 0, stream>>>(h1, u, vq, rowptr, srcs, Wcf + 4096, bc + 64,
                                        Wff, bf, nullptr, out);
}

// Round 17
// 316.849 us; speedup vs baseline: 1.2271x; 1.2271x over previous
//
#include <hip/hip_runtime.h>

#define NN 100000
#define NE 1000000
#define NCLS 32
#define NB 391            // ceil(NN/256)
#define GN 32             // nodes per k_agg group
#define NGROUPS (NN/GN)   // 3125
#define UVG ((NN+63)/64)  // 1563 uv groups of 64 nodes

typedef __bf16 bf16x8 __attribute__((ext_vector_type(8)));
typedef float f32x16 __attribute__((ext_vector_type(16)));

__device__ __forceinline__ int imin(int a, int b){ return a < b ? a : b; }

// pack hi16 of two f32 into one u32: {hi16(f1) : hi16(f0)}  (f0 -> low half)
__device__ __forceinline__ unsigned pk_hi(unsigned u1, unsigned u0){
  return __builtin_amdgcn_perm(u1, u0, 0x07060302u);
}
__device__ __forceinline__ unsigned pk_lo(float f0, float f1, unsigned u0, unsigned u1){
  float r0 = f0 - __uint_as_float(u0 & 0xFFFF0000u);
  float r1 = f1 - __uint_as_float(u1 & 0xFFFF0000u);
  return pk_hi(__float_as_uint(r1), __float_as_uint(r0));
}
__device__ __forceinline__ f32x16 mfma_b(uint4 a, uint4 b, f32x16 c){
  bf16x8 av, bv;
  __builtin_memcpy(&av, &a, 16);
  __builtin_memcpy(&bv, &b, 16);
  return __builtin_amdgcn_mfma_f32_32x32x16_bf16(av, bv, c, 0, 0, 0);
}
__device__ __forceinline__ int crow(int r, int half){ return (r&3) + 8*(r>>2) + 4*half; }

// ---------- one-shot setup: all weight fragments + bc + zero deg ----------
__global__ void k_setup(const float* __restrict__ W1_lin, const float* __restrict__ b1_lin,
                        const float* __restrict__ W1_post, const float* __restrict__ b1_post,
                        const float* __restrict__ W2_lin, const float* __restrict__ b2_lin,
                        const float* __restrict__ W2_post, const float* __restrict__ b2_post,
                        const float* __restrict__ W1_pre, const float* __restrict__ W2_pre,
                        const float* __restrict__ Wf,
                        uint4* __restrict__ Wcf, uint4* __restrict__ Wpf,
                        uint4* __restrict__ Wff, float* __restrict__ bc,
                        int* __restrict__ deg){
  const int blk = blockIdx.x, tid = threadIdx.x;
  if (blk < 16){
    int i = blk*256 + tid;                    // [0, 4096)
    int layer = i >> 11;
    int t = (i >> 10) & 1, step = (i >> 6) & 15, lane = i & 63;
    const float* Wlin  = layer ? W2_lin  : W1_lin;
    const float* Wpost = layer ? W2_post : W1_post;
    int col = t*32 + (lane & 31);
    int k0 = step*16 + ((lane >> 5) << 3);
    unsigned hi[4], lo[4];
    for (int p = 0; p < 4; p++){
      float f0 = 0.f, f1 = 0.f;
      for (int j = 0; j < 64; j++){
        float wl = Wlin[col*64 + j];
        f0 += wl * Wpost[j*256 + k0 + 2*p];
        f1 += wl * Wpost[j*256 + k0 + 2*p + 1];
      }
      unsigned u0 = __float_as_uint(f0), u1 = __float_as_uint(f1);
      hi[p] = pk_hi(u1, u0);
      lo[p] = pk_lo(f0, f1, u0, u1);
    }
    uint4* base = Wcf + layer*4096;
    base[t*1024     + step*64 + lane] = make_uint4(hi[0],hi[1],hi[2],hi[3]);
    base[(2+t)*1024 + step*64 + lane] = make_uint4(lo[0],lo[1],lo[2],lo[3]);
  } else if (blk < 24){
    int i = (blk-16)*256 + tid;               // [0, 2048)
    int layer = i >> 10;
    int t = (i >> 8) & 3, st = (i >> 6) & 3, lane = i & 63;
    const float* Wpre = layer ? W2_pre : W1_pre;
    int col = t*32 + (lane & 31);             // 0..127 (u | v)
    int o = col & 63, koff = (col >> 6) * 64;
    int k0 = st*16 + ((lane >> 5) << 3);
    unsigned hi[4], lo[4];
    for (int p = 0; p < 4; p++){
      float f0 = Wpre[o*128 + koff + k0 + 2*p];
      float f1 = Wpre[o*128 + koff + k0 + 2*p + 1];
      unsigned u0 = __float_as_uint(f0), u1 = __float_as_uint(f1);
      hi[p] = pk_hi(u1, u0);
      lo[p] = pk_lo(f0, f1, u0, u1);
    }
    uint4* base = Wpf + layer*2048 + t*512;
    base[st*64 + lane]       = make_uint4(hi[0],hi[1],hi[2],hi[3]);
    base[256 + st*64 + lane] = make_uint4(lo[0],lo[1],lo[2],lo[3]);
  } else if (blk == 24){
    int st = tid >> 6, lane = tid & 63;       // 256 threads exactly
    int cls = lane & 31;
    int k0 = st*16 + ((lane >> 5) << 3);
    unsigned hi[4], lo[4];
    for (int p = 0; p < 4; p++){
      float f0 = Wf[cls*64 + k0 + 2*p];
      float f1 = Wf[cls*64 + k0 + 2*p + 1];
      unsigned u0 = __float_as_uint(f0), u1 = __float_as_uint(f1);
      hi[p] = pk_hi(u1, u0);
      lo[p] = pk_lo(f0, f1, u0, u1);
    }
    Wff[st*64 + lane]       = make_uint4(hi[0],hi[1],hi[2],hi[3]);
    Wff[256 + st*64 + lane] = make_uint4(lo[0],lo[1],lo[2],lo[3]);
  } else if (blk == 25){
    if (tid < 128){
      int layer = tid >> 6, o = tid & 63;
      const float* Wlin  = layer ? W2_lin  : W1_lin;
      const float* blin  = layer ? b2_lin  : b1_lin;
      const float* bpost = layer ? b2_post : b1_post;
      float s = blin[o];
      for (int j = 0; j < 64; j++) s += Wlin[o*64+j] * bpost[j];
      bc[tid] = s;
    }
  } else {
    int i = (blk-26)*256 + tid;
    if (i < NN) deg[i] = 0;
  }
}

// ---------- CSR build ----------
__global__ void k_deg(const int* __restrict__ dst, int* __restrict__ deg){
  int e = blockIdx.x*256 + threadIdx.x;
  if (e < NE) atomicAdd(&deg[dst[e]], 1);
}

__global__ void k_scan1(const int* __restrict__ deg, int* __restrict__ inc,
                        int* __restrict__ part){
  __shared__ int s[256];
  int tid = threadIdx.x;
  int i = blockIdx.x*256 + tid;
  s[tid] = (i < NN) ? deg[i] : 0;
  __syncthreads();
  for (int off = 1; off < 256; off <<= 1){
    int t = (tid >= off) ? s[tid-off] : 0;
    __syncthreads();
    s[tid] += t;
    __syncthreads();
  }
  inc[i] = s[tid];
  if (tid == 255) part[blockIdx.x] = s[255];
}

// each block re-scans all partials in LDS, then emits rowptr + cursor
__global__ void k_scan23(const int* __restrict__ inc, const int* __restrict__ part,
                         const int* __restrict__ deg,
                         int* __restrict__ rowptr, int* __restrict__ cursor){
  __shared__ int s[512];
  int tid = threadIdx.x;
  s[tid] = (tid < NB) ? part[tid] : 0;
  __syncthreads();
  for (int off = 1; off < 512; off <<= 1){
    int t = (tid >= off) ? s[tid-off] : 0;
    __syncthreads();
    s[tid] += t;
    __syncthreads();
  }
  int b = blockIdx.x;
  int base = b ? s[b-1] : 0;
  if (tid < 256){
    int i = b*256 + tid;
    if (i < NN){
      int inclusive = inc[i] + base;
      rowptr[i+1] = inclusive;
      cursor[i] = inclusive - deg[i];
    }
  }
  if (b == 0 && tid == 0) rowptr[0] = 0;
}

__global__ void k_scatter(const int* __restrict__ src, const int* __restrict__ dst,
                          int* __restrict__ cursor, int* __restrict__ srcs){
  int e = blockIdx.x*256 + threadIdx.x;
  if (e < NE){
    int d = dst[e];
    int p = atomicAdd(&cursor[d], 1);
    srcs[p] = src[e];
  }
}

// ---------- per-node pre-transform via MFMA: u(f32) = WpreL*x + b ; vq(bf16-pair) = WpreR*x ----------
__global__ __launch_bounds__(512, 4) void k_uv(
    const float* __restrict__ xin, const uint4* __restrict__ Wpf,
    const float* __restrict__ bpre, float* __restrict__ u, unsigned* __restrict__ vq){
  __shared__ __align__(16) unsigned XH[64*36];
  __shared__ __align__(16) unsigned XL[64*36];
  const int tid = threadIdx.x;
  const int lane = tid & 63;
  const int w = tid >> 6;
  const int t = w >> 1, rg = w & 1;
  const int cc = lane & 31, half = lane >> 5;
  const int col = t*32 + cc;
  uint4 wfr[2][4];
  {
    const uint4* p = Wpf + t*512;
    #pragma unroll
    for (int s = 0; s < 2; s++)
      #pragma unroll
      for (int st = 0; st < 4; st++) wfr[s][st] = p[s*256 + st*64 + lane];
  }
  const float bias = (t < 2) ? bpre[col] : 0.f;
  const int dcol = col & 63;
  const int srow = tid >> 3, sq = tid & 7;

  for (int g = blockIdx.x; g < UVG; g += gridDim.x){
    const int n0 = g*64;
    __syncthreads();                 // previous group's A-frag reads done
    {
      const int node = n0 + srow;
      float4 a = {0,0,0,0}, b = {0,0,0,0};
      if (node < NN){
        a = *(const float4*)&xin[(size_t)node*64 + sq*8];
        b = *(const float4*)&xin[(size_t)node*64 + sq*8 + 4];
      }
      unsigned ax = __float_as_uint(a.x), ay = __float_as_uint(a.y);
      unsigned az = __float_as_uint(a.z), aw = __float_as_uint(a.w);
      unsigned bx = __float_as_uint(b.x), by = __float_as_uint(b.y);
      unsigned bz = __float_as_uint(b.z), bw = __float_as_uint(b.w);
      uint4 hi, lo;
      hi.x = pk_hi(ay, ax); lo.x = pk_lo(a.x, a.y, ax, ay);
      hi.y = pk_hi(aw, az); lo.y = pk_lo(a.z, a.w, az, aw);
      hi.z = pk_hi(by, bx); lo.z = pk_lo(b.x, b.y, bx, by);
      hi.w = pk_hi(bw, bz); lo.w = pk_lo(b.z, b.w, bz, bw);
      *(uint4*)&XH[srow*36 + sq*4] = hi;
      *(uint4*)&XL[srow*36 + sq*4] = lo;
    }
    __syncthreads();
    f32x16 acc = {};
    const int arow = (rg*32 + cc)*36 + half*4;
    #pragma unroll
    for (int st = 0; st < 4; st++){
      uint4 ah = *(const uint4*)&XH[arow + st*8];
      uint4 al = *(const uint4*)&XL[arow + st*8];
      acc = mfma_b(ah, wfr[0][st], acc);
      acc = mfma_b(al, wfr[0][st], acc);
      acc = mfma_b(ah, wfr[1][st], acc);
    }
    if (t < 2){
      #pragma unroll
      for (int r = 0; r < 16; r++){
        int row = n0 + rg*32 + crow(r, half);
        if (row < NN) u[(size_t)row*64 + dcol] = acc[r] + bias;
      }
    } else {
      // pack adjacent columns (even dcol holds pair) -> bf16x2 with RNE
      #pragma unroll
      for (int r = 0; r < 16; r++){
        float val = acc[r];
        float pv = __shfl_xor(val, 1, 64);
        if ((cc & 1) == 0){
          unsigned pk;
          asm("v_cvt_pk_bf16_f32 %0, %1, %2" : "=v"(pk) : "v"(val), "v"(pv));
          int row = n0 + rg*32 + crow(r, half);
          if (row < NN) vq[(size_t)row*32 + (dcol >> 1)] = pk;
        }
      }
    }
  }
}

// ---------- fused CSR gather + MFMA post GEMM (+ fused classifier if EPI==1) ----------
// 512 thr / 8 waves, GN=32; each wave gathers 4 nodes as 2 interleaved pairs
// with rolling index prefetch (round-10 proven operating point: VGPR 32,
// 4 blocks/CU, zero spill).
template<int EPI>
__global__ __launch_bounds__(512, 8) void k_agg(
    const float* __restrict__ xin, const float* __restrict__ u,
    const unsigned* __restrict__ vq,
    const int* __restrict__ rowptr, const int* __restrict__ srcs,
    const uint4* __restrict__ Wcf, const float* __restrict__ bcv,
    const uint4* __restrict__ Wff, const float* __restrict__ bfv,
    float* __restrict__ hout, float* __restrict__ outp){
  __shared__ __align__(16) unsigned Zh[GN*132];
  __shared__ __align__(16) unsigned Zl[GN*132];
  const int tid = threadIdx.x;
  const int lane = tid & 63;
  const int w = tid >> 6;
  const int c = lane & 31;
  const int h = lane >> 5;
  const float bias = (w < 2) ? bcv[w*32 + c] : 0.f;
  const uint4* WH = Wcf + w*1024;
  const uint4* WL = Wcf + (2+w)*1024;

  for (int g = blockIdx.x; g < NGROUPS; g += gridDim.x){
    const int n0 = g*GN;
    __syncthreads();                 // previous group's LDS reads done
    // ---- gather: wave w -> rows w*4 .. w*4+3, processed as 2 interleaved pairs
    #pragma unroll
    for (int pr = 0; pr < 2; pr++){
      const int nA = n0 + w*4 + pr*2;
      const int r0A = rowptr[nA],   r1A = rowptr[nA+1];
      const int r0B = rowptr[nA+1], r1B = rowptr[nA+2];
      int jA = r0A + h, jB = r0B + h;
      int a0=0,a1=0,a2=0,a3=0, b0=0,b1=0,b2=0,b3=0;
      bool hA = (jA + 6 < r1A), hB = (jB + 6 < r1B);
      if (hA){ a0=srcs[jA]; a1=srcs[jA+2]; a2=srcs[jA+4]; a3=srcs[jA+6]; }
      if (hB){ b0=srcs[jB]; b1=srcs[jB+2]; b2=srcs[jB+4]; b3=srcs[jB+6]; }
      #pragma unroll
      for (int sub = 0; sub < 2; sub++){
        const int node = nA + sub;
        const int r1 = sub ? r1B : r1A;
        int jj = sub ? jB : jA;
        int e0 = sub?b0:a0, e1 = sub?b1:a1, e2 = sub?b2:a2, e3 = sub?b3:a3;
        bool have = sub ? hB : hA;
        float Sx = 0.f, Sy = 0.f;
        float Mx = -3.402823466e+38f, My = Mx;
        while (have){
          int njj = jj + 8;
          bool more = (njj + 6 < r1);
          int f0=0,f1=0,f2=0,f3=0;
          if (more){ f0=srcs[njj]; f1=srcs[njj+2]; f2=srcs[njj+4]; f3=srcs[njj+6]; }
          unsigned p0 = vq[(size_t)e0*32 + c];
          unsigned p1 = vq[(size_t)e1*32 + c];
          unsigned p2 = vq[(size_t)e2*32 + c];
          unsigned p3 = vq[(size_t)e3*32 + c];
          float x0 = __uint_as_float(p0 << 16), y0 = __uint_as_float(p0 & 0xFFFF0000u);
          float x1 = __uint_as_float(p1 << 16), y1 = __uint_as_float(p1 & 0xFFFF0000u);
          float x2 = __uint_as_float(p2 << 16), y2 = __uint_as_float(p2 & 0xFFFF0000u);
          float x3 = __uint_as_float(p3 << 16), y3 = __uint_as_float(p3 & 0xFFFF0000u);
          Sx += (x0 + x1) + (x2 + x3);
          Sy += (y0 + y1) + (y2 + y3);
          Mx = fmaxf(Mx, fmaxf(fmaxf(x0, x1), fmaxf(x2, x3)));
          My = fmaxf(My, fmaxf(fmaxf(y0, y1), fmaxf(y2, y3)));
          jj = njj; e0=f0; e1=f1; e2=f2; e3=f3; have = more;
        }
        for (; jj < r1; jj += 2){
          unsigned p = vq[(size_t)srcs[jj]*32 + c];
          float x0 = __uint_as_float(p << 16), y0 = __uint_as_float(p & 0xFFFF0000u);
          Sx += x0; Sy += y0;
          Mx = fmaxf(Mx, x0); My = fmaxf(My, y0);
        }
        Sx += __shfl_xor(Sx, 32, 64);
        Sy += __shfl_xor(Sy, 32, 64);
        Mx = fmaxf(Mx, __shfl_xor(Mx, 32, 64));
        My = fmaxf(My, __shfl_xor(My, 32, 64));

        const float2 up = *(const float2*)&u[(size_t)node*64 + 2*c];
        const float2 xv = *(const float2*)&xin[(size_t)node*64 + 2*c];
        const int d = r1 - (sub ? r0B : r0A);
        float2 z1, z2, z3;
        if (d > 0){
          float fd = (float)d;
          z1.x = up.x + Sx/fd;  z1.y = up.y + Sy/fd;
          z2.x = up.x + Mx;     z2.y = up.y + My;
          z3.x = fmaf(fd, up.x, Sx); z3.y = fmaf(fd, up.y, Sy);
        } else {
          z1.x=z1.y=z2.x=z2.y=z3.x=z3.y=0.f;   // PyG empty-segment semantics
        }
        const int row = w*4 + pr*2 + sub;
        float2 q[4] = {xv, z1, z2, z3};
        #pragma unroll
        for (int qq = 0; qq < 4; qq++){
          unsigned u0 = __float_as_uint(q[qq].x), u1 = __float_as_uint(q[qq].y);
          if (h == 0) Zh[row*132 + qq*32 + c] = pk_hi(u1, u0);
          else        Zl[row*132 + qq*32 + c] = pk_lo(q[qq].x, q[qq].y, u0, u1);
        }
      }
    }
    __syncthreads();
    // ---- post-GEMM MFMA: waves 0,1
    f32x16 acc = {};
    if (w < 2){
      const int arow = c*132 + h*4;
      #pragma unroll 4
      for (int s = 0; s < 16; s++){
        uint4 ah = *(const uint4*)&Zh[arow + s*8];
        uint4 al = *(const uint4*)&Zl[arow + s*8];
        uint4 bh = WH[s*64 + lane];
        uint4 bl = WL[s*64 + lane];
        acc = mfma_b(ah, bh, acc);
        acc = mfma_b(al, bh, acc);
        acc = mfma_b(ah, bl, acc);
      }
      if (EPI == 0){
        #pragma unroll
        for (int r = 0; r < 16; r++){
          float val = fmaxf(acc[r] + bias, 0.f);
          hout[(size_t)(n0 + crow(r,h))*64 + w*32 + c] = val;
        }
      }
    }
    if (EPI == 1){
      __syncthreads();               // BOTH MFMA waves done READING Zh/Zl
      if (w < 2){
        float* HF = (float*)Zh;      // now safe to reuse Zh
        #pragma unroll
        for (int r = 0; r < 16; r++){
          float val = fmaxf(acc[r] + bias, 0.f);
          HF[crow(r,h)*64 + w*32 + c] = val;
        }
      }
      __syncthreads();               // HF complete
      {
        const float* HF = (const float*)Zh;
        unsigned* HH = Zl;
        unsigned* HL = Zl + 1152;
        const int row = tid >> 4, p4 = tid & 15;
        float4 f = *(const float4*)&HF[row*64 + p4*4];
        unsigned f0 = __float_as_uint(f.x), f1 = __float_as_uint(f.y);
        unsigned f2 = __float_as_uint(f.z), f3 = __float_as_uint(f.w);
        HH[row*36 + p4*2]   = pk_hi(f1, f0);
        HH[row*36 + p4*2+1] = pk_hi(f3, f2);
        HL[row*36 + p4*2]   = pk_lo(f.x, f.y, f0, f1);
        HL[row*36 + p4*2+1] = pk_lo(f.z, f.w, f2, f3);
      }
      __syncthreads();               // HH/HL complete
      if (w == 0){
        f32x16 ac2 = {};
        const unsigned* HH = Zl;
        const unsigned* HL = Zl + 1152;
        const int arow = c*36 + h*4;
        #pragma unroll
        for (int st = 0; st < 4; st++){
          uint4 ah = *(const uint4*)&HH[arow + st*8];
          uint4 al = *(const uint4*)&HL[arow + st*8];
          uint4 bh = Wff[st*64 + lane];
          uint4 bl = Wff[256 + st*64 + lane];
          ac2 = mfma_b(ah, bh, ac2);
          ac2 = mfma_b(al, bh, ac2);
          ac2 = mfma_b(ah, bl, ac2);
        }
        const float bcls = bfv[c];
        #pragma unroll
        for (int r = 0; r < 16; r++)
          outp[(size_t)(n0 + crow(r,h))*NCLS + c] = ac2[r] + bcls;
      }
    }
  }
}

extern "C" void kernel_launch(void* const* d_in, const int* in_sizes, int n_in,
                              void* d_out, int out_size, void* d_ws, size_t ws_size,
                              hipStream_t stream){
  const float* x      = (const float*)d_in[0];
  const int*   ei     = (const int*)  d_in[1];
  const int*   src    = ei;
  const int*   dst    = ei + NE;
  const float* W1_pre = (const float*)d_in[2];
  const float* b1_pre = (const float*)d_in[3];
  const float* W1_post= (const float*)d_in[4];
  const float* b1_post= (const float*)d_in[5];
  const float* W1_lin = (const float*)d_in[6];
  const float* b1_lin = (const float*)d_in[7];
  const float* W2_pre = (const float*)d_in[8];
  const float* b2_pre = (const float*)d_in[9];
  const float* W2_post= (const float*)d_in[10];
  const float* b2_post= (const float*)d_in[11];
  const float* W2_lin = (const float*)d_in[12];
  const float* b2_lin = (const float*)d_in[13];
  const float* Wf     = (const float*)d_in[14];
  const float* bf     = (const float*)d_in[15];
  float* out = (float*)d_out;

  size_t off = 0;
  char* ws = (char*)d_ws;
  auto alloc = [&](size_t bytes){ void* p = ws + off; off += (bytes + 255) & ~(size_t)255; return p; };
  int*      deg    = (int*)     alloc(NN*4);
  int*      rowptr = (int*)     alloc((NN+1)*4);
  int*      cursor = (int*)     alloc(NN*4);
  int*      inc    = (int*)     alloc(NB*256*4);
  int*      part   = (int*)     alloc(512*4);
  int*      srcs   = (int*)     alloc((size_t)NE*4);
  float*    u      = (float*)   alloc((size_t)NN*64*4);
  unsigned* vq     = (unsigned*)alloc((size_t)NN*32*4);
  float*    h1     = (float*)   alloc((size_t)NN*64*4);
  uint4*    Wcf    = (uint4*)   alloc(2*4096*16);
  uint4*    Wpf    = (uint4*)   alloc(4096*16);
  uint4*    Wff    = (uint4*)   alloc(512*16);
  float*    bc     = (float*)   alloc(128*4);

  // 1. all weight fragments + bc + zero deg, in one kernel
  k_setup<<<417, 256, 0, stream>>>(W1_lin, b1_lin, W1_post, b1_post,
                                   W2_lin, b2_lin, W2_post, b2_post,
                                   W1_pre, W2_pre, Wf, Wcf, Wpf, Wff, bc, deg);
  // 2-5. CSR build
  k_deg    <<<(NE+255)/256, 256, 0, stream>>>(dst, deg);
  k_scan1  <<<NB, 256, 0, stream>>>(deg, inc, part);
  k_scan23 <<<NB, 512, 0, stream>>>(inc, part, deg, rowptr, cursor);
  k_scatter<<<(NE+255)/256, 256, 0, stream>>>(src, dst, cursor, srcs);

  // layer 1
  k_uv    <<<UVG, 512, 0, stream>>>(x, Wpf, b1_pre, u, vq);
  k_agg<0><<<NGROUPS, 512, 0, stream>>>(x, u, vq, rowptr, srcs, Wcf, bc,
                                        nullptr, nullptr, h1, nullptr);

  // layer 2 (+ fused classifier; h2 never hits HBM)
  k_uv    <<<UVG, 512, 0, stream>>>(h1, Wpf + 2048, b2_pre, u, vq);
  k_agg<1><<<NGROUPS, 512, 0, stream>>>(h1, u, vq, rowptr, srcs, Wcf + 4096, bc + 64,
                                        Wff, bf, nullptr, out);
}